// Round 6
// baseline (94.770 us; speedup 1.0000x reference)
//
#include <hip/hip_runtime.h>
#include <math.h>

// N=1024, D=128, tau=1, beta=1. SINGLE kernel node.
//   grid 1025 x 256: block 0 = spinner/finalizer, blocks 1..1024 = workers.
//   Worker wid=bx-1: i_tile = wid&63 (16 rows), p = (wid>>6)&1, jc = wid>>7 (128 cols).
//   fp32 loads straight from d_in -> bf16 frags + exact fp32 norms -> MFMA dots ->
//   d2 = nx+ny-2dot -> dm -> exp-rowsum. Release-stores 16 row-partials (+ pos when
//   the chunk holds the diagonal), then release-stores a magic tag.
//   Spinner polls all 1024 tags (magic != 0xAA poison), then den=sum_jc, 
//   contrib = pos - log(den), reduces, plain-stores out[0..2].
#define NN 1024
#define DD 128
#define MAGIC 0x5F3C2A11u

typedef __bf16 bf16x8 __attribute__((ext_vector_type(8)));
typedef float  floatx4 __attribute__((ext_vector_type(4)));

__global__ __launch_bounds__(256) void align_one(
    const float* __restrict__ x, const float* __restrict__ lp,
    const float* __restrict__ aug, float* __restrict__ out,
    float* __restrict__ denom_part /* [2][8][1024] */,
    float* __restrict__ posbuf     /* [2][1024] */,
    unsigned* __restrict__ tags    /* [1024] */)
{
    const int tid  = threadIdx.x;
    const int bx   = blockIdx.x;

    if (bx == 0) {
        // ---------------- spinner / finalizer ----------------
        // poll 4 tags per thread until all == MAGIC
        for (;;) {
            unsigned a = __hip_atomic_load(&tags[tid],       __ATOMIC_ACQUIRE, __HIP_MEMORY_SCOPE_AGENT);
            unsigned b = __hip_atomic_load(&tags[tid + 256], __ATOMIC_ACQUIRE, __HIP_MEMORY_SCOPE_AGENT);
            unsigned c = __hip_atomic_load(&tags[tid + 512], __ATOMIC_ACQUIRE, __HIP_MEMORY_SCOPE_AGENT);
            unsigned d = __hip_atomic_load(&tags[tid + 768], __ATOMIC_ACQUIRE, __HIP_MEMORY_SCOPE_AGENT);
            if (a == MAGIC && b == MAGIC && c == MAGIC && d == MAGIC) break;
            __builtin_amdgcn_s_sleep(2);
        }
        __syncthreads();
        const int w    = tid >> 6;
        const int lane = tid & 63;
        float sum0 = 0.f, sum1 = 0.f;
#pragma unroll
        for (int k = 0; k < 4; ++k) {
            const int row = tid + k * 256;
#pragma unroll
            for (int p = 0; p < 2; ++p) {
                float den = 0.f;
#pragma unroll
                for (int jc = 0; jc < 8; ++jc)
                    den += __hip_atomic_load(&denom_part[(size_t)(p * 8 + jc) * NN + row],
                                             __ATOMIC_RELAXED, __HIP_MEMORY_SCOPE_AGENT);
                const float po = __hip_atomic_load(&posbuf[p * NN + row],
                                             __ATOMIC_RELAXED, __HIP_MEMORY_SCOPE_AGENT);
                const float c2 = po - __logf(den);
                if (p) sum1 += c2; else sum0 += c2;
            }
        }
#pragma unroll
        for (int m = 1; m < 64; m <<= 1) {
            sum0 += __shfl_xor(sum0, m);
            sum1 += __shfl_xor(sum1, m);
        }
        __shared__ float s0[4], s1[4];
        if (lane == 0) { s0[w] = sum0; s1[w] = sum1; }
        __syncthreads();
        if (tid == 0) {
            const float inv = 1.0f / (float)NN;
            const float c  = (s0[0] + s0[1] + s0[2] + s0[3]) * inv;  // center loss
            const float ia = (s1[0] + s1[1] + s1[2] + s1[3]) * inv;  // instance loss
            out[0] = c + ia;   // alignment_loss (beta = 1)
            out[1] = c;
            out[2] = ia;
        }
        return;
    }

    // ---------------- worker ----------------
    const float SCALE = 0.08838834764831845f;  // 1/sqrt(128)
    const int wid = bx - 1;
    const int it  = wid & 63;          // i-tile
    const int p   = (wid >> 6) & 1;    // pair
    const int jc  = wid >> 7;          // j-chunk
    const float* __restrict__ Y = p ? aug : lp;

    const int i0   = it * 16;
    const int w    = tid >> 6;    // wave 0..3
    const int lane = tid & 63;
    const int col  = lane & 15;   // A-frag row / C col
    const int quad = lane >> 4;   // 0..3

    // ---- A fragments (x row i0+col, k = c*32 + quad*8 + [0..7]) + exact norm ----
    const float* xrow = x + (size_t)(i0 + col) * DD + quad * 8;
    bf16x8 afrag[4];
    float nx_own = 0.f;
#pragma unroll
    for (int c = 0; c < 4; ++c) {
        const float4 u0 = *(const float4*)(xrow + c * 32);
        const float4 u1 = *(const float4*)(xrow + c * 32 + 4);
        nx_own += u0.x*u0.x + u0.y*u0.y + u0.z*u0.z + u0.w*u0.w;
        nx_own += u1.x*u1.x + u1.y*u1.y + u1.z*u1.z + u1.w*u1.w;
        bf16x8 f;
        f[0]=(__bf16)u0.x; f[1]=(__bf16)u0.y; f[2]=(__bf16)u0.z; f[3]=(__bf16)u0.w;
        f[4]=(__bf16)u1.x; f[5]=(__bf16)u1.y; f[6]=(__bf16)u1.z; f[7]=(__bf16)u1.w;
        afrag[c] = f;
    }
    nx_own += __shfl_xor(nx_own, 16);
    nx_own += __shfl_xor(nx_own, 32);     // full ||x_(i0+col)||^2
    float nxr[4];
#pragma unroll
    for (int r = 0; r < 4; ++r) nxr[r] = __shfl(nx_own, quad * 4 + r);

    float denom[4] = {0.f, 0.f, 0.f, 0.f};
    float pos[4]   = {0.f, 0.f, 0.f, 0.f};

#pragma unroll
    for (int t = 0; t < 2; ++t) {
        const int j0 = jc * 128 + t * 64 + w * 16;
        const float* yrow = Y + (size_t)(j0 + col) * DD + quad * 8;
        bf16x8 bfrag[4];
        float ny_own = 0.f;
#pragma unroll
        for (int c = 0; c < 4; ++c) {
            const float4 u0 = *(const float4*)(yrow + c * 32);
            const float4 u1 = *(const float4*)(yrow + c * 32 + 4);
            ny_own += u0.x*u0.x + u0.y*u0.y + u0.z*u0.z + u0.w*u0.w;
            ny_own += u1.x*u1.x + u1.y*u1.y + u1.z*u1.z + u1.w*u1.w;
            bf16x8 f;
            f[0]=(__bf16)u0.x; f[1]=(__bf16)u0.y; f[2]=(__bf16)u0.z; f[3]=(__bf16)u0.w;
            f[4]=(__bf16)u1.x; f[5]=(__bf16)u1.y; f[6]=(__bf16)u1.z; f[7]=(__bf16)u1.w;
            bfrag[c] = f;
        }
        ny_own += __shfl_xor(ny_own, 16);
        ny_own += __shfl_xor(ny_own, 32);   // ||y_(j0+col)||^2

        floatx4 acc = {0.f, 0.f, 0.f, 0.f};
#pragma unroll
        for (int c = 0; c < 4; ++c)
            acc = __builtin_amdgcn_mfma_f32_16x16x32_bf16(afrag[c], bfrag[c], acc, 0, 0, 0);

#pragma unroll
        for (int r = 0; r < 4; ++r) {
            const int row = quad * 4 + r;          // C: col=lane&15, row=quad*4+reg
            float d2 = fmaf(-2.f, acc[r], nxr[r] + ny_own);
            d2 = fmaxf(d2, 0.f);
            const float dm = SCALE * sqrtf(d2);
            denom[r] += __expf(dm);
            if (j0 + col == i0 + row) pos[r] = dm;
        }
    }

    // reduce across the 16 cols of each quad group
#pragma unroll
    for (int r = 0; r < 4; ++r) {
#pragma unroll
        for (int m = 1; m < 16; m <<= 1) {
            denom[r] += __shfl_xor(denom[r], m);
            pos[r]   += __shfl_xor(pos[r], m);
        }
    }

    // cross-wave combine
    __shared__ float ld_den[4][16];
    __shared__ float ld_pos[4][16];
    if (col == 0) {
#pragma unroll
        for (int r = 0; r < 4; ++r) {
            ld_den[w][quad * 4 + r] = denom[r];
            ld_pos[w][quad * 4 + r] = pos[r];
        }
    }
    __syncthreads();
    if (tid < 16) {
        const float den = ld_den[0][tid] + ld_den[1][tid] + ld_den[2][tid] + ld_den[3][tid];
        __hip_atomic_store(&denom_part[(size_t)(p * 8 + jc) * NN + i0 + tid], den,
                           __ATOMIC_RELEASE, __HIP_MEMORY_SCOPE_AGENT);
        if (jc == (it >> 3)) {   // this chunk holds the diagonal for rows i0..i0+15
            const float po = ld_pos[0][tid] + ld_pos[1][tid] + ld_pos[2][tid] + ld_pos[3][tid];
            __hip_atomic_store(&posbuf[p * NN + i0 + tid], po,
                               __ATOMIC_RELEASE, __HIP_MEMORY_SCOPE_AGENT);
        }
    }
    __syncthreads();
    if (tid == 0)
        __hip_atomic_store(&tags[wid], MAGIC, __ATOMIC_RELEASE, __HIP_MEMORY_SCOPE_AGENT);
}

extern "C" void kernel_launch(void* const* d_in, const int* in_sizes, int n_in,
                              void* d_out, int out_size, void* d_ws, size_t ws_size,
                              hipStream_t stream) {
    const float* x   = (const float*)d_in[0];
    const float* aug = (const float*)d_in[1];
    const float* lp  = (const float*)d_in[2];
    float* out       = (float*)d_out;

    float*    denom_part = (float*)d_ws;                       // 64 KB
    float*    posbuf     = (float*)((char*)d_ws + 65536);      //  8 KB
    unsigned* tags       = (unsigned*)((char*)d_ws + 73728);   //  4 KB

    align_one<<<1025, 256, 0, stream>>>(x, lp, aug, out, denom_part, posbuf, tags);
}

// Round 7
// 68.539 us; speedup vs baseline: 1.3827x; 1.3827x over previous
//
#include <hip/hip_runtime.h>
#include <math.h>

// N=1024, D=128, tau=1, beta=1. Three-node pipeline (best measured structure, R2):
//   prep: fp32 -> bf16 for all 3 matrices ONCE + exact fp32 row norms.
//   pair: grid (64,2,8) x 256 thr; bf16 MFMA dots; d2 = nx+ny-2dot;
//         dm = sqrt(d2)/sqrt(D); partial exp-rowsums -> ws.
//   fin : 1 block x 256; den = sum_jc partials; contrib = pos - log(den); reduce.
// Lesson R6: cross-block store/poll sync costs ~40us (L2 eviction-bound) on gfx950;
// kernel-boundary ordering is the cheap sync.
#define NN 1024
#define DD 128

typedef __bf16 bf16x8 __attribute__((ext_vector_type(8)));
typedef __bf16 bf16x4 __attribute__((ext_vector_type(4)));
typedef float  floatx4 __attribute__((ext_vector_type(4)));

// ---------------- prep: fp32 -> bf16 + row norms ----------------
// 384 blocks x 256 thr; wave = 2 rows (32 lanes/row, float4 per lane).
__global__ __launch_bounds__(256) void align_prep(
    const float* __restrict__ x, const float* __restrict__ lp,
    const float* __restrict__ aug, __bf16* __restrict__ mats,
    float* __restrict__ norms)
{
    const int w    = threadIdx.x >> 6;
    const int lane = threadIdx.x & 63;
    const int gw   = blockIdx.x * 4 + w;            // 0..1535 (2 rows each)
    const int grow = gw * 2 + (lane >> 5);          // 0..3071
    const int a    = grow >> 10;                    // matrix 0..2
    const int r    = grow & 1023;                   // row
    const int c4   = (lane & 31) * 4;               // col offset
    const float* src = (a == 0 ? x : (a == 1 ? lp : aug)) + (size_t)r * DD + c4;
    const float4 v = *(const float4*)src;
    float sq = v.x * v.x + v.y * v.y + v.z * v.z + v.w * v.w;
    bf16x4 b;
    b[0] = (__bf16)v.x; b[1] = (__bf16)v.y; b[2] = (__bf16)v.z; b[3] = (__bf16)v.w;
    *(bf16x4*)(mats + ((size_t)a << 17) + (size_t)r * DD + c4) = b;
#pragma unroll
    for (int m = 1; m < 32; m <<= 1) sq += __shfl_xor(sq, m);   // within 32-lane row group
    if ((lane & 31) == 0) norms[a * NN + r] = sq;
}

// ---------------- pair: partial softmax-denoms (proven R2 kernel) ----------------
__global__ __launch_bounds__(256) void align_pair_kernel(
    const __bf16* __restrict__ mats, const float* __restrict__ norms,
    float* __restrict__ denom_part /* [2][8][1024] */,
    float* __restrict__ posbuf     /* [2][1024] */)
{
    const float SCALE = 0.08838834764831845f;  // 1/sqrt(128)
    const int bx = blockIdx.x;     // i-tile (16 rows)
    const int p  = blockIdx.y;     // 0: x vs lp, 1: x vs aug
    const int jc = blockIdx.z;     // j-chunk (128 cols)
    const __bf16* __restrict__ A = mats;
    const __bf16* __restrict__ B = mats + (size_t)(p ? 2 : 1) * (NN * DD);
    const float*  __restrict__ nx = norms;
    const float*  __restrict__ ny = norms + (p ? 2 : 1) * NN;

    const int i0   = bx * 16;
    const int tid  = threadIdx.x;
    const int w    = tid >> 6;
    const int lane = tid & 63;
    const int col  = lane & 15;
    const int quad = lane >> 4;

    const __bf16* arow = A + (size_t)(i0 + col) * DD + quad * 8;
    bf16x8 afrag[4];
#pragma unroll
    for (int c = 0; c < 4; ++c) afrag[c] = *(const bf16x8*)(arow + c * 32);
    const float4 nxr = *(const float4*)(nx + i0 + quad * 4);

    float denom[4] = {0.f, 0.f, 0.f, 0.f};
    float pos[4]   = {0.f, 0.f, 0.f, 0.f};

#pragma unroll
    for (int t = 0; t < 2; ++t) {
        const int j0 = jc * 128 + t * 64 + w * 16;
        const __bf16* brow = B + (size_t)(j0 + col) * DD + quad * 8;
        bf16x8 bfrag[4];
#pragma unroll
        for (int c = 0; c < 4; ++c) bfrag[c] = *(const bf16x8*)(brow + c * 32);
        const float nyv = ny[j0 + col];

        floatx4 acc = {0.f, 0.f, 0.f, 0.f};
#pragma unroll
        for (int c = 0; c < 4; ++c)
            acc = __builtin_amdgcn_mfma_f32_16x16x32_bf16(afrag[c], bfrag[c], acc, 0, 0, 0);

#pragma unroll
        for (int r = 0; r < 4; ++r) {
            const int row = quad * 4 + r;          // C: col=lane&15, row=quad*4+reg
            float d2 = fmaf(-2.f, acc[r], nxr[r] + nyv);
            d2 = fmaxf(d2, 0.f);
            const float dm = SCALE * sqrtf(d2);
            denom[r] += __expf(dm);
            if (j0 + col == i0 + row) pos[r] = dm;
        }
    }

#pragma unroll
    for (int r = 0; r < 4; ++r) {
#pragma unroll
        for (int m = 1; m < 16; m <<= 1) {
            denom[r] += __shfl_xor(denom[r], m);
            pos[r]   += __shfl_xor(pos[r], m);
        }
    }

    __shared__ float ld_den[4][16];
    __shared__ float ld_pos[4][16];
    if (col == 0) {
#pragma unroll
        for (int r = 0; r < 4; ++r) {
            ld_den[w][quad * 4 + r] = denom[r];
            ld_pos[w][quad * 4 + r] = pos[r];
        }
    }
    __syncthreads();
    if (tid < 16) {
        const float den = ld_den[0][tid] + ld_den[1][tid] + ld_den[2][tid] + ld_den[3][tid];
        denom_part[(size_t)(p * 8 + jc) * NN + i0 + tid] = den;
        if (jc == (bx >> 3)) {   // this chunk holds the diagonal for rows i0..i0+15
            const float po = ld_pos[0][tid] + ld_pos[1][tid] + ld_pos[2][tid] + ld_pos[3][tid];
            posbuf[p * NN + i0 + tid] = po;
        }
    }
}

// ---------------- fin: 1 block x 256, float4 row-quads ----------------
__global__ __launch_bounds__(256) void align_fin(
    const float* __restrict__ denom_part, const float* __restrict__ posbuf,
    float* __restrict__ out)
{
    const int tid  = threadIdx.x;
    const int w    = tid >> 6;
    const int lane = tid & 63;
    const int r0   = tid * 4;          // rows r0..r0+3
    float sum0 = 0.f, sum1 = 0.f;
#pragma unroll
    for (int p = 0; p < 2; ++p) {
        float4 den = {0.f, 0.f, 0.f, 0.f};
#pragma unroll
        for (int jc = 0; jc < 8; ++jc) {
            const float4 d = *(const float4*)(denom_part + (size_t)(p * 8 + jc) * NN + r0);
            den.x += d.x; den.y += d.y; den.z += d.z; den.w += d.w;
        }
        const float4 po = *(const float4*)(posbuf + p * NN + r0);
        const float c = (po.x - __logf(den.x)) + (po.y - __logf(den.y))
                      + (po.z - __logf(den.z)) + (po.w - __logf(den.w));
        if (p) sum1 += c; else sum0 += c;
    }
#pragma unroll
    for (int m = 1; m < 64; m <<= 1) {
        sum0 += __shfl_xor(sum0, m);
        sum1 += __shfl_xor(sum1, m);
    }
    __shared__ float s0[4], s1[4];
    if (lane == 0) { s0[w] = sum0; s1[w] = sum1; }
    __syncthreads();
    if (tid == 0) {
        const float inv = 1.0f / (float)NN;
        const float c  = (s0[0] + s0[1] + s0[2] + s0[3]) * inv;  // center loss
        const float ia = (s1[0] + s1[1] + s1[2] + s1[3]) * inv;  // instance loss
        out[0] = c + ia;     // alignment_loss (beta = 1)
        out[1] = c;
        out[2] = ia;
    }
}

extern "C" void kernel_launch(void* const* d_in, const int* in_sizes, int n_in,
                              void* d_out, int out_size, void* d_ws, size_t ws_size,
                              hipStream_t stream) {
    const float* x   = (const float*)d_in[0];
    const float* aug = (const float*)d_in[1];
    const float* lp  = (const float*)d_in[2];
    float* out       = (float*)d_out;

    char* ws = (char*)d_ws;
    __bf16* mats      = (__bf16*)ws;                       // [3][1024][128] bf16 = 768 KB
    float*  norms     = (float*)(ws + 786432);             // [3][1024]            12 KB
    float*  denom_par = (float*)(ws + 798720);             // [2][8][1024]         64 KB
    float*  posbuf    = (float*)(ws + 864256);             // [2][1024]             8 KB

    align_prep<<<384, 256, 0, stream>>>(x, lp, aug, mats, norms);
    align_pair_kernel<<<dim3(64, 2, 8), 256, 0, stream>>>(mats, norms, denom_par, posbuf);
    align_fin<<<1, 256, 0, stream>>>(denom_par, posbuf, out);
}